// Round 15
// baseline (137.867 us; speedup 1.0000x reference)
//
#include <hip/hip_runtime.h>
#include <hip/hip_fp16.h>
#include <cmath>

#define BATCH 1024
#define SOUT 36336
#define POUT 10596
#define PS_COLS 10464   // s params compacted (dec2 block removed)
#define PP_COLS 10596
#define PD_COLS 25872   // s dec2 block (W 32x784 + b 784)

typedef __attribute__((ext_vector_type(8))) short bf16x8;
typedef __attribute__((ext_vector_type(4))) float f32x4;
typedef __attribute__((ext_vector_type(2))) float f32x2;

__device__ __forceinline__ float sigmoidf_(float x){ return 1.0f/(1.0f+__expf(-x)); }
__device__ __forceinline__ float reluf_(float x){ return x>0.0f?x:0.0f; }
__device__ __forceinline__ float fast_tanhf(float x){
  float e = __expf(2.f*x);
  return 1.f - 2.f/(e + 1.f);
}
__device__ __forceinline__ f32x2 h2f(__half2 h){
  float2 f = __half22float2(h);
  f32x2 r; r.x = f.x; r.y = f.y; return r;
}

__device__ __forceinline__ void bf16split(float f, unsigned short& hi, unsigned short& lo){
  unsigned u = __float_as_uint(f);
  hi = (unsigned short)(u >> 16);
  float fhi = __uint_as_float(((unsigned)hi) << 16);
  float rem = f - fhi;                       // exact in fp32
  lo = (unsigned short)(__float_as_uint(rem) >> 16);
}

// ---------------- K1: backbone hidden h2 (s and p), emitted as bf16 hi/lo ---------
__global__ __launch_bounds__(128) void k_backbone(
    const float* __restrict__ z,
    const float* __restrict__ sw1, const float* __restrict__ sb1,
    const float* __restrict__ sw2, const float* __restrict__ sb2,
    const float* __restrict__ pw1, const float* __restrict__ pb1,
    const float* __restrict__ pw2, const float* __restrict__ pb2,
    unsigned short* __restrict__ h2s_hi, unsigned short* __restrict__ h2s_lo,
    unsigned short* __restrict__ h2p_hi, unsigned short* __restrict__ h2p_lo)
{
  __shared__ float zsh[32];
  __shared__ float h1sh[2][64];
  const int b = blockIdx.x;
  const int tid = threadIdx.x;
  const int g = tid >> 6, o = tid & 63;
  if (tid < 32) zsh[tid] = z[b*32 + tid];
  __syncthreads();
  const float* w1 = g ? pw1 : sw1;
  const float* b1 = g ? pb1 : sb1;
  float acc = b1[o];
  #pragma unroll
  for (int i=0;i<32;i++) acc += zsh[i]*w1[i*64+o];
  h1sh[g][o] = reluf_(acc);
  __syncthreads();
  const float* w2 = g ? pw2 : sw2;
  const float* b2 = g ? pb2 : sb2;
  float acc2 = b2[o];
  #pragma unroll
  for (int i=0;i<64;i++) acc2 += h1sh[g][i]*w2[i*64+o];
  float v = reluf_(acc2);
  unsigned short hi, lo;
  bf16split(v, hi, lo);
  (g ? h2p_hi : h2s_hi)[b*64+o] = hi;
  (g ? h2p_lo : h2s_lo)[b*64+o] = lo;
}

// ---------------- K2: all three params GEMMs on MFMA, fp16 outputs ----------------
__global__ __launch_bounds__(256, 2) void k_params5(
    const unsigned short* __restrict__ h2s_hi, const unsigned short* __restrict__ h2s_lo,
    const unsigned short* __restrict__ h2p_hi, const unsigned short* __restrict__ h2p_lo,
    const float* __restrict__ sw3, const float* __restrict__ sb3,
    const float* __restrict__ pw3, const float* __restrict__ pb3,
    __half* __restrict__ Ps, __half* __restrict__ Pp, __half* __restrict__ Pd)
{
  __shared__ __align__(16) unsigned short wth[64][72];   // w3^T hi, padded
  __shared__ __align__(16) unsigned short wtl[64][72];   // w3^T lo
  int xt = blockIdx.x;
  const unsigned short *ahi, *alo;
  const float *w3, *b3;
  __half* outH;
  int OC, thr, off, stride;
  if (xt < 164){
    ahi=h2s_hi; alo=h2s_lo; w3=sw3; b3=sb3; outH=Ps;
    OC=PS_COLS; thr=4192; off=25872; stride=SOUT;
  } else if (xt < 330){
    xt -= 164;
    ahi=h2p_hi; alo=h2p_lo; w3=pw3; b3=pb3; outH=Pp;
    OC=PP_COLS; thr=0x40000000; off=0; stride=POUT;
  } else {
    xt -= 330;
    ahi=h2s_hi; alo=h2s_lo; w3=sw3; b3=sb3; outH=Pd;
    OC=PD_COLS; thr=0; off=4192; stride=SOUT;
  }
  const int c0 = xt*64;
  const int tid = threadIdx.x;

  for (int idx=tid; idx<4096; idx+=256){
    int j = idx >> 6, cc = idx & 63;
    int c = c0 + cc; if (c > OC-1) c = OC-1;
    int src = (c < thr) ? c : c + off;
    float f = w3[(size_t)j*stride + src];
    unsigned short hi, lo;
    bf16split(f, hi, lo);
    wth[cc][j] = hi; wtl[cc][j] = lo;
  }
  __syncthreads();

  const int wv = tid >> 6, l = tid & 63;
  const int lr = l & 15, lq = l >> 4;

  bf16x8 Bh[2][4], Bl[2][4];
  #pragma unroll
  for (int ks=0; ks<2; ks++){
    #pragma unroll
    for (int ct=0; ct<4; ct++){
      const int row = ct*16 + lr;
      const int joff = ks*32 + lq*8;
      Bh[ks][ct] = *reinterpret_cast<const bf16x8*>(&wth[row][joff]);
      Bl[ks][ct] = *reinterpret_cast<const bf16x8*>(&wtl[row][joff]);
    }
  }
  float bv[4];
  #pragma unroll
  for (int ct=0; ct<4; ct++){
    int c = c0 + ct*16 + lr; if (c > OC-1) c = OC-1;
    int src = (c < thr) ? c : c + off;
    bv[ct] = b3[src];
  }

  for (int bsub=0; bsub<16; bsub++){
    const int arow = bsub*64 + wv*16 + lr;
    const unsigned short* ah = ahi + arow*64;
    const unsigned short* al = alo + arow*64;
    bf16x8 Ah0 = *reinterpret_cast<const bf16x8*>(ah + lq*8);
    bf16x8 Ah1 = *reinterpret_cast<const bf16x8*>(ah + 32 + lq*8);
    bf16x8 Al0 = *reinterpret_cast<const bf16x8*>(al + lq*8);
    bf16x8 Al1 = *reinterpret_cast<const bf16x8*>(al + 32 + lq*8);
    #pragma unroll
    for (int ct=0; ct<4; ct++){
      f32x4 acc = {0.f,0.f,0.f,0.f};
      acc = __builtin_amdgcn_mfma_f32_16x16x32_bf16(Ah0, Bh[0][ct], acc, 0,0,0);
      acc = __builtin_amdgcn_mfma_f32_16x16x32_bf16(Ah1, Bh[1][ct], acc, 0,0,0);
      acc = __builtin_amdgcn_mfma_f32_16x16x32_bf16(Ah0, Bl[0][ct], acc, 0,0,0);
      acc = __builtin_amdgcn_mfma_f32_16x16x32_bf16(Ah1, Bl[1][ct], acc, 0,0,0);
      acc = __builtin_amdgcn_mfma_f32_16x16x32_bf16(Al0, Bh[0][ct], acc, 0,0,0);
      acc = __builtin_amdgcn_mfma_f32_16x16x32_bf16(Al1, Bh[1][ct], acc, 0,0,0);
      const int c = c0 + ct*16 + lr;
      if (c < OC){
        const int r0 = bsub*64 + wv*16 + lq*4;
        const float bb = bv[ct];
        outH[(size_t)(r0+0)*OC + c] = __float2half(acc[0] + bb);
        outH[(size_t)(r0+1)*OC + c] = __float2half(acc[1] + bb);
        outH[(size_t)(r0+2)*OC + c] = __float2half(acc[2] + bb);
        outH[(size_t)(r0+3)*OC + c] = __float2half(acc[3] + bb);
      }
    }
  }
}

// ---------------- K3: hyper-GRU seq, wave-per-net, fp16-packed register weights ---
// 160 weight values packed as 80 __half2 VGPRs -> whole set fits the ~120-VGPR
// allocation the compiler insists on -> no remat from L2/L3 per substep.
// wX packing: lanes <32 hold wR2 (candidate), lanes >=32 hold wK2 (xh).
__global__ __launch_bounds__(128, 2) void k_seq2(
    const __half* __restrict__ Ps, const __half* __restrict__ Pp,
    float* __restrict__ Dout, float* __restrict__ Aout)
{
  __shared__ float xvT[64], xvI[64], initZ[64], hst[64];
  __shared__ float psA[128], e2s[64], rhs[64], xhs[64], d1s[32], d2w[132];

  const int b = blockIdx.x;
  const int tid = threadIdx.x;
  const int g = tid >> 6, l = tid & 63;
  const int o = l & 31, h = l >> 5;
  const __half* Gp = g ? (Pp + (size_t)b*PP_COLS) : (Ps + (size_t)b*PS_COLS);
  const int rnn = g ? 4324 : 4192;

  __half2 wE1[16], wED[16], wK[16], wR[16], wX[16];
  float bE1, bED, bK, bK2;

  bE1 = __half2float(Gp[2048 + o]);
  bK  = __half2float(Gp[rnn + 6144 + l]);
  bK2 = __half2float(Gp[rnn + 6144 + 64 + o]);
  const int xb = (l < 32) ? (rnn + 3072) : rnn;   // wR2 : wK2
  #pragma unroll
  for (int i=0;i<16;i++){
    wE1[i] = __halves2half2(Gp[h*1024 + (2*i)*32 + o],   Gp[h*1024 + (2*i+1)*32 + o]);
    wK[i]  = __halves2half2(Gp[rnn + (2*i)*96 + l],      Gp[rnn + (2*i+1)*96 + l]);
    wR[i]  = __halves2half2(Gp[rnn + 3072 + (2*i)*96 + l],
                            Gp[rnn + 3072 + (2*i+1)*96 + l]);
    wX[i]  = __halves2half2(Gp[xb + (2*i)*96 + 64 + o],  Gp[xb + (2*i+1)*96 + 64 + o]);
  }
  if (l < 32){
    #pragma unroll
    for (int i=0;i<16;i++)
      wED[i] = __halves2half2(Gp[2080 + (2*i)*32 + o], Gp[2080 + (2*i+1)*32 + o]);
    bED = __half2float(Gp[3104 + o]);
  } else {
    #pragma unroll
    for (int i=0;i<16;i++)
      wED[i] = __halves2half2(Gp[3136 + (2*i)*32 + o], Gp[3136 + (2*i+1)*32 + o]);
    bED = __half2float(Gp[4160 + o]);
  }
  if (g == 1){                          // p dec2 weights -> LDS (tiny)
    for (int idx=l; idx<132; idx+=64) d2w[idx] = __half2float(Gp[4192 + idx]);
  }

  if (tid < 64) hst[tid] = 0.f;
  if (tid < 32) initZ[tid] = __half2float(Ps[(size_t)b*PS_COLS + 10432 + tid]);
  else if (tid < 64) initZ[tid] = __half2float(Pp[(size_t)b*PP_COLS + 10564 + (tid-32)]);
  __syncthreads();
  if (tid < 64) xvT[tid] = initZ[tid];
  __syncthreads();

  auto substep = [&](const float* xv, int aidx, int t16, bool isTop){
    // 1: e1 K-half psums (all lanes)
    {
      f32x2 s0 = {0.f,0.f}, s1 = {0.f,0.f};
      const float4* x4 = reinterpret_cast<const float4*>(&xv[h*32]);
      #pragma unroll
      for (int i=0;i<8;i++){
        float4 v = x4[i];
        f32x2 vlo; vlo.x=v.x; vlo.y=v.y;
        f32x2 vhi; vhi.x=v.z; vhi.y=v.w;
        s0 += vlo*h2f(wE1[2*i]);
        s1 += vhi*h2f(wE1[2*i+1]);
      }
      psA[g*64 + l] = (s0.x+s0.y)+(s1.x+s1.y) + ((l<32)?bE1:0.f);
    }
    // 2: e2 = relu(e1) @ Wenc2 + b (lanes 0-31) — psA same-wave, lgkm-ordered
    if (l < 32){
      f32x2 s0 = {0.f,0.f}, s1 = {0.f,0.f};
      const float4* p0 = reinterpret_cast<const float4*>(&psA[g*64]);
      const float4* p1 = reinterpret_cast<const float4*>(&psA[g*64+32]);
      #pragma unroll
      for (int i=0;i<8;i++){
        float4 u = p0[i], v = p1[i];
        f32x2 elo; elo.x=reluf_(u.x+v.x); elo.y=reluf_(u.y+v.y);
        f32x2 ehi; ehi.x=reluf_(u.z+v.z); ehi.y=reluf_(u.w+v.w);
        s0 += elo*h2f(wED[2*i]);
        s1 += ehi*h2f(wED[2*i+1]);
      }
      e2s[g*32 + o] = (s0.x+s0.y)+(s1.x+s1.y) + bED;
    }
    // 3: gxh (all lanes); xh col 64+o + r-gate (lanes 32-63)
    float gxh;
    {
      f32x2 k0={0.f,0.f},k1={0.f,0.f},r0={0.f,0.f},r1={0.f,0.f},x0={0.f,0.f},x1={0.f,0.f};
      const float4* e4 = reinterpret_cast<const float4*>(&e2s[g*32]);
      const float4* h4 = reinterpret_cast<const float4*>(&hst[g*32]);
      #pragma unroll
      for (int i=0;i<8;i++){
        float4 u = e4[i], v = h4[i];
        f32x2 ulo; ulo.x=u.x; ulo.y=u.y;
        f32x2 uhi; uhi.x=u.z; uhi.y=u.w;
        f32x2 vlo; vlo.x=v.x; vlo.y=v.y;
        f32x2 vhi; vhi.x=v.z; vhi.y=v.w;
        k0 += ulo*h2f(wK[2*i]); k1 += uhi*h2f(wK[2*i+1]);
        r0 += vlo*h2f(wR[2*i]); r1 += vhi*h2f(wR[2*i+1]);
        x0 += ulo*h2f(wX[2*i]); x1 += uhi*h2f(wX[2*i+1]);  // wX=wK2 on l>=32
      }
      gxh = (k0.x+k0.y)+(k1.x+k1.y) + bK + (r0.x+r0.y)+(r1.x+r1.y);
      if (l >= 32){
        xhs[g*32 + o] = (x0.x+x0.y)+(x1.x+x1.y) + bK2;
        float rg = sigmoidf_(gxh);
        rhs[g*32 + o] = rg * hst[g*32 + o];
      }
    }
    // 5: z-gate + candidate + h-update (lanes 0-31); wX=wR2 here
    if (l < 32){
      float zg = sigmoidf_(gxh);
      f32x2 s0 = {0.f,0.f}, s1 = {0.f,0.f};
      const float4* r4 = reinterpret_cast<const float4*>(&rhs[g*32]);
      #pragma unroll
      for (int i=0;i<8;i++){
        float4 v = r4[i];
        f32x2 vlo; vlo.x=v.x; vlo.y=v.y;
        f32x2 vhi; vhi.x=v.z; vhi.y=v.w;
        s0 += vlo*h2f(wX[2*i]);
        s1 += vhi*h2f(wX[2*i+1]);
      }
      float hh = fast_tanhf(xhs[g*32+o] + (s0.x+s0.y)+(s1.x+s1.y));
      float ho = hst[g*32+o];
      float hn = zg*ho + (1.f-zg)*hh;
      hst[g*32+o] = hn;
      if (isTop){ xvT[g*32+o] = hn; xvI[g*32+o] = initZ[g*32+o]; }
      else        xvI[g*32+o] = hn;
    }
    // 6: dec1 (lanes 32-63) on NEW h — same-wave ordering
    if (l >= 32 && (g==1 || t16 >= 0)){
      f32x2 s0 = {0.f,0.f}, s1 = {0.f,0.f};
      const float4* h4 = reinterpret_cast<const float4*>(&hst[g*32]);
      #pragma unroll
      for (int i=0;i<8;i++){
        float4 v = h4[i];
        f32x2 vlo; vlo.x=v.x; vlo.y=v.y;
        f32x2 vhi; vhi.x=v.z; vhi.y=v.w;
        s0 += vlo*h2f(wED[2*i]);
        s1 += vhi*h2f(wED[2*i+1]);
      }
      float d = reluf_((s0.x+s0.y)+(s1.x+s1.y) + bED);
      if (g == 0) Dout[((size_t)t16*BATCH + b)*32 + o] = d;
      else d1s[o] = d;
    }
    // 7: p dec2 -> a (wave1 lanes 32-35), weights from LDS
    if (g == 1 && l >= 32 && l < 36){
      const int c = l - 32;
      float acc = d2w[128 + c];
      #pragma unroll
      for (int i=0;i<32;i++) acc += d1s[i]*d2w[i*4 + c];
      Aout[((size_t)aidx*BATCH + b)*4 + c] = acc;
    }
    __syncthreads();   // xvT/xvI visible to the other wave
  };

  for (int t=0;t<4;t++){
    substep(xvT, t, -1, true);
    for (int k=0;k<4;k++){
      substep(xvI, 4 + t*4 + k, t*4 + k, false);
    }
  }
}

// ---------------- bilinear samplers (fp32 and fp16 LDS images) ----------------
__device__ __forceinline__ float fetchpix(const float* __restrict__ img, int y, int x){
  if ((unsigned)y >= 28u || (unsigned)x >= 28u) return 0.0f;
  return img[y*28 + x];
}
__device__ __forceinline__ float fetchpixh(const __half* __restrict__ img, int y, int x){
  if ((unsigned)y >= 28u || (unsigned)x >= 28u) return 0.0f;
  return __half2float(img[y*28 + x]);
}
#define BILIN_BODY(FETCH) \
  const float stepv = 2.0f/27.0f; \
  float gxv = -1.0f + stepv*(float)c; \
  float gyv = -1.0f + stepv*(float)r; \
  float srcx = (a0 + 1.0f)*gxv + a2; \
  float srcy = (a1 + 1.0f)*gyv + a3; \
  float px = (srcx + 1.0f)*13.5f; \
  float py = (srcy + 1.0f)*13.5f; \
  float x0f = floorf(px), y0f = floorf(py); \
  float wx = px - x0f, wy = py - y0f; \
  int x0 = (int)x0f, y0 = (int)y0f; \
  float v00 = FETCH(img, y0,   x0); \
  float v01 = FETCH(img, y0,   x0+1); \
  float v10 = FETCH(img, y0+1, x0); \
  float v11 = FETCH(img, y0+1, x0+1); \
  return v00*(1.0f-wx)*(1.0f-wy) + v01*wx*(1.0f-wy) \
       + v10*(1.0f-wx)*wy + v11*wx*wy;

__device__ __forceinline__ float bilin(const float* __restrict__ img,
    float a0, float a1, float a2, float a3, int r, int c){ BILIN_BODY(fetchpix) }
__device__ __forceinline__ float bilinh(const __half* __restrict__ img,
    float a0, float a1, float a2, float a3, int r, int c){ BILIN_BODY(fetchpixh) }

// ---------------- K4: fused decode: xhat (fp16 Pd stream) + both composites --------
__global__ __launch_bounds__(256, 4) void k_dec(
    const __half* __restrict__ Pd, const float* __restrict__ Dm,
    const float* __restrict__ Am, float* __restrict__ outp)
{
  extern __shared__ float lds[];
  float*  o0 = lds;                                      // 3136 f32
  float*  Da = lds + 3136;                               // 528
  float*  av = lds + 3664;                               // 80
  __half* xh = reinterpret_cast<__half*>(lds + 3744);    // 16*784 halves (25088 B)
  const int b = blockIdx.x;
  const int tid = threadIdx.x;

  for (int idx=tid; idx<512; idx+=256){
    int t = idx >> 5, i = idx & 31;
    Da[t*33 + i] = Dm[((size_t)t*BATCH + b)*32 + i];
  }
  if (tid < 16) Da[tid*33 + 32] = 1.0f;
  if (tid < 80) av[tid] = Am[((size_t)(tid>>2)*BATCH + b)*4 + (tid&3)];

  f32x2 accL[16], accH[16];
  #pragma unroll
  for (int t=0;t<16;t++){
    accL[t].x=0.f; accL[t].y=0.f;
    accH[t].x=0.f; accH[t].y=0.f;
  }
  __syncthreads();

  const __half* Pdb = Pd + (size_t)b*PD_COLS;
  #pragma unroll 3
  for (int i=0;i<33;i++){
    const __half* row = Pdb + (i<32 ? i*784 : 25088);
    f32x2 vlo = {0.f,0.f}, vhi = {0.f,0.f};
    if (tid < 196){
      const __half2 h0 = reinterpret_cast<const __half2*>(row)[tid*2];
      const __half2 h1 = reinterpret_cast<const __half2*>(row)[tid*2+1];
      float2 f0 = __half22float2(h0), f1 = __half22float2(h1);
      vlo.x = f0.x; vlo.y = f0.y; vhi.x = f1.x; vhi.y = f1.y;
    }
    #pragma unroll
    for (int t=0;t<16;t++){
      float da = Da[t*33 + i];
      f32x2 d2; d2.x = da; d2.y = da;
      accL[t] += d2*vlo;
      accH[t] += d2*vhi;
    }
  }
  if (tid < 196){
    #pragma unroll
    for (int t=0;t<16;t++){
      __half2* dst = reinterpret_cast<__half2*>(xh + t*784 + tid*4);
      dst[0] = __floats2half2_rn(accL[t].x, accL[t].y);
      dst[1] = __floats2half2_rn(accH[t].x, accH[t].y);
    }
  }
  __syncthreads();

  // level-0 composite
  for (int idx=tid; idx<4*784; idx+=256){
    int t = idx / 784, pix = idx - t*784;
    int r = pix / 28, c = pix - r*28;
    float s = 0.f;
    #pragma unroll
    for (int k=0;k<4;k++){
      const float* ap = av + (4 + t*4 + k)*4;
      s += bilinh(xh + (t*4+k)*784, ap[0], ap[1], ap[2], ap[3], r, c);
    }
    o0[t*784 + pix] = s;
  }
  __syncthreads();

  // level-1 composite -> d_out
  for (int idx=tid; idx<784; idx+=256){
    int r = idx / 28, c = idx - r*28;
    float s = 0.f;
    #pragma unroll
    for (int t=0;t<4;t++){
      const float* ap = av + t*4;
      s += bilin(o0 + t*784, ap[0], ap[1], ap[2], ap[3], r, c);
    }
    outp[(size_t)b*784 + idx] = s;
  }
}

extern "C" void kernel_launch(void* const* d_in, const int* in_sizes, int n_in,
                              void* d_out, int out_size, void* d_ws, size_t ws_size,
                              hipStream_t stream)
{
  const float* z   = (const float*)d_in[1];
  const float* sw1 = (const float*)d_in[2];
  const float* sb1 = (const float*)d_in[3];
  const float* sw2 = (const float*)d_in[4];
  const float* sb2 = (const float*)d_in[5];
  const float* sw3 = (const float*)d_in[6];
  const float* sb3 = (const float*)d_in[7];
  const float* pw1 = (const float*)d_in[8];
  const float* pb1 = (const float*)d_in[9];
  const float* pw2 = (const float*)d_in[10];
  const float* pb2 = (const float*)d_in[11];
  const float* pw3 = (const float*)d_in[12];
  const float* pb3 = (const float*)d_in[13];

  float* ws = (float*)d_ws;
  __half* Ps = (__half*)ws;                          // 1024*10464 halves (5,357,568 f32)
  __half* Pp = (__half*)(ws + 5357568);              // 1024*10596 halves (5,425,152 f32)
  __half* Pd = (__half*)(ws + 10782720);             // 1024*25872 halves (13,246,464 f32)
  float*  Dm = ws + 24029184;                        // 16*1024*32
  float*  Am = ws + 24553472;                        // 20*1024*4
  unsigned short* h2s_hi = (unsigned short*)(ws + 24635392);   // 1024*64 each
  unsigned short* h2s_lo = h2s_hi + 65536;
  unsigned short* h2p_hi = h2s_hi + 131072;
  unsigned short* h2p_lo = h2s_hi + 196608;
  float* outp = (float*)d_out;

  (void)hipFuncSetAttribute(reinterpret_cast<const void*>(k_dec),
                            hipFuncAttributeMaxDynamicSharedMemorySize,
                            40064);

  hipLaunchKernelGGL(k_backbone, dim3(1024), dim3(128), 0, stream,
                     z, sw1,sb1,sw2,sb2, pw1,pb1,pw2,pb2,
                     h2s_hi, h2s_lo, h2p_hi, h2p_lo);
  hipLaunchKernelGGL(k_params5, dim3(735), dim3(256), 0, stream,
                     h2s_hi, h2s_lo, h2p_hi, h2p_lo,
                     sw3, sb3, pw3, pb3, Ps, Pp, Pd);
  hipLaunchKernelGGL(k_seq2, dim3(1024), dim3(128), 0, stream,
                     Ps, Pp, Dm, Am);
  hipLaunchKernelGGL(k_dec, dim3(1024), dim3(256), 40064, stream,
                     Pd, Dm, Am, outp);
}